// Round 13
// baseline (15590.207 us; speedup 1.0000x reference)
//
#include <hip/hip_runtime.h>
#include <math.h>

#define FEAT 512
#define NS   4096
#define NQ   8192
#define NC   64
#define G4   2048   // 4*FEAT
#define SENT 1.0e30f

using bf16x8 = __attribute__((ext_vector_type(8))) short;
using f32x4  = __attribute__((ext_vector_type(4))) float;

__device__ __forceinline__ float sigf(float x) { return 1.0f / (1.0f + expf(-x)); }

// RNE f32 -> bf16 hi, residual -> bf16 lo
__device__ __forceinline__ void split_bf16(float x, unsigned short& hi, unsigned short& lo) {
    unsigned u = __float_as_uint(x);
    unsigned r = u + 0x7FFFu + ((u >> 16) & 1u);
    hi = (unsigned short)(r >> 16);
    float res = x - __uint_as_float((unsigned)hi << 16);
    unsigned u2 = __float_as_uint(res);
    unsigned r2 = u2 + 0x7FFFu + ((u2 >> 16) & 1u);
    lo = (unsigned short)(r2 >> 16);
}

// ---------------- small utility kernels ----------------
__global__ void kzero(float* __restrict__ dst, int n) {
    int i = blockIdx.x * blockDim.x + threadIdx.x;
    int st = gridDim.x * blockDim.x;
    for (; i < n; i += st) dst[i] = 0.0f;
}

__global__ void kfill(float* __restrict__ dst, float v, int n) {
    int i = blockIdx.x * blockDim.x + threadIdx.x;
    int st = gridDim.x * blockDim.x;
    for (; i < n; i += st) dst[i] = v;
}

__global__ void split_arr(const float* __restrict__ in, unsigned short* __restrict__ oh,
                          unsigned short* __restrict__ ol, int n) {
    int i = blockIdx.x * blockDim.x + threadIdx.x;
    int st = gridDim.x * blockDim.x;
    for (; i < n; i += st) {
        unsigned short h, l;
        split_bf16(in[i], h, l);
        oh[i] = h; ol[i] = l;
    }
}

// pack Wpack pair: [k*4+g][0:1536] = [Wc_ih[g*512+k][0:1024] | Wc_hh[g*512+k][0:512]]
__global__ void pack_w(unsigned short* __restrict__ Wph, unsigned short* __restrict__ Wpl,
                       float* __restrict__ bpack,
                       const float* __restrict__ Wc_ih, const float* __restrict__ Wc_hh,
                       const float* __restrict__ bc) {
    int i = blockIdx.x * blockDim.x + threadIdx.x;
    int st = gridDim.x * blockDim.x;
    const int n = G4 * 1536;
    for (; i < n; i += st) {
        int R = i / 1536, j = i - R * 1536;
        int k = R >> 2, g = R & 3;
        int row2 = g * FEAT + k;
        float v = (j < 1024) ? Wc_ih[(size_t)row2 * 1024 + j]
                             : Wc_hh[(size_t)row2 * FEAT + (j - 1024)];
        unsigned short h, l;
        split_bf16(v, h, l);
        Wph[i] = h; Wpl[i] = l;
        if (j == 0) bpack[R] = bc[row2];
    }
}

// ================= f32-staged MFMA GEMM: C = A @ B^T (+bias) — Phase A =================
template<int BIAS>
__global__ __launch_bounds__(256)
void mm_abt_f32(const float* __restrict__ A0, const float* __restrict__ B,
                int lda, int ldb, float* __restrict__ C, int ldc,
                const float* __restrict__ bias, int K)
{
    __shared__ unsigned short Ah[128][40], Al[128][40], Bh[128][40], Bl[128][40];
    const int tid = threadIdx.x;
    const int row0 = blockIdx.y * 128, col0 = blockIdx.x * 128;
    const int l = tid & 63;
    const int wm = ((tid >> 6) >> 1) * 64, wn = ((tid >> 6) & 1) * 64;
    const int fr = l & 15, fk = (l >> 4) * 8;

    f32x4 acc[4][4];
#pragma unroll
    for (int mt = 0; mt < 4; ++mt)
#pragma unroll
        for (int nt = 0; nt < 4; ++nt) acc[mt][nt] = (f32x4){0.f, 0.f, 0.f, 0.f};

    for (int k0 = 0; k0 < K; k0 += 32) {
#pragma unroll
        for (int p = 0; p < 4; ++p) {
            int flat = p * 256 + tid;
            int ar = flat >> 3, aq = (flat & 7) * 4;
            float4 v = *(const float4*)(A0 + (size_t)(row0 + ar) * lda + k0 + aq);
            unsigned short h0,h1,h2,h3,q0,q1,q2,q3;
            split_bf16(v.x, h0, q0); split_bf16(v.y, h1, q1);
            split_bf16(v.z, h2, q2); split_bf16(v.w, h3, q3);
            *(short4*)&Ah[ar][aq] = make_short4((short)h0,(short)h1,(short)h2,(short)h3);
            *(short4*)&Al[ar][aq] = make_short4((short)q0,(short)q1,(short)q2,(short)q3);
        }
#pragma unroll
        for (int p = 0; p < 4; ++p) {
            int flat = p * 256 + tid;
            int br = flat >> 3, bq = (flat & 7) * 4;
            float4 v = *(const float4*)(B + (size_t)(col0 + br) * ldb + k0 + bq);
            unsigned short h0,h1,h2,h3,q0,q1,q2,q3;
            split_bf16(v.x, h0, q0); split_bf16(v.y, h1, q1);
            split_bf16(v.z, h2, q2); split_bf16(v.w, h3, q3);
            *(short4*)&Bh[br][bq] = make_short4((short)h0,(short)h1,(short)h2,(short)h3);
            *(short4*)&Bl[br][bq] = make_short4((short)q0,(short)q1,(short)q2,(short)q3);
        }
        __syncthreads();

        bf16x8 ah[4], al4[4], bh[4], bl4[4];
#pragma unroll
        for (int mt = 0; mt < 4; ++mt) {
            ah[mt]  = *(const bf16x8*)&Ah[wm + mt * 16 + fr][fk];
            al4[mt] = *(const bf16x8*)&Al[wm + mt * 16 + fr][fk];
        }
#pragma unroll
        for (int nt = 0; nt < 4; ++nt) {
            bh[nt]  = *(const bf16x8*)&Bh[wn + nt * 16 + fr][fk];
            bl4[nt] = *(const bf16x8*)&Bl[wn + nt * 16 + fr][fk];
        }
#pragma unroll
        for (int mt = 0; mt < 4; ++mt)
#pragma unroll
            for (int nt = 0; nt < 4; ++nt) {
                acc[mt][nt] = __builtin_amdgcn_mfma_f32_16x16x32_bf16(ah[mt],  bh[nt],  acc[mt][nt], 0, 0, 0);
                acc[mt][nt] = __builtin_amdgcn_mfma_f32_16x16x32_bf16(al4[mt], bh[nt],  acc[mt][nt], 0, 0, 0);
                acc[mt][nt] = __builtin_amdgcn_mfma_f32_16x16x32_bf16(ah[mt],  bl4[nt], acc[mt][nt], 0, 0, 0);
            }
        __syncthreads();
    }
#pragma unroll
    for (int mt = 0; mt < 4; ++mt) {
        int row = row0 + wm + mt * 16 + (l >> 4) * 4;
#pragma unroll
        for (int nt = 0; nt < 4; ++nt) {
            int col = col0 + wn + nt * 16 + fr;
            float bv = BIAS ? bias[col] : 0.0f;
#pragma unroll
            for (int j = 0; j < 4; ++j)
                C[(size_t)(row + j) * ldc + col] = acc[mt][nt][j] + bv;
        }
    }
}

// ================= MFMA GEMM: C = A @ B^T (+bias), A f32 on-the-fly, B pair =================
// TRISRC: A = [A0|A1|A2] f32 concat along K (512 each). (fallback path)
template<int BIAS, int TRISRC>
__global__ __launch_bounds__(256)
void mm_abt2(const float* __restrict__ A0, const float* __restrict__ A1,
             const float* __restrict__ A2,
             const unsigned short* __restrict__ Bh, const unsigned short* __restrict__ Bl,
             int lda, int ldb, float* __restrict__ C, int ldc,
             const float* __restrict__ bias, int K)
{
    __shared__ unsigned short Ah[128][40], Al[128][40], Bhs[128][40], Bls[128][40];
    const int tid = threadIdx.x;
    const int row0 = blockIdx.y * 128, col0 = blockIdx.x * 128;
    const int l = tid & 63;
    const int wm = ((tid >> 6) >> 1) * 64, wn = ((tid >> 6) & 1) * 64;
    const int fr = l & 15, fk = (l >> 4) * 8;

    f32x4 acc[4][4];
#pragma unroll
    for (int mt = 0; mt < 4; ++mt)
#pragma unroll
        for (int nt = 0; nt < 4; ++nt) acc[mt][nt] = (f32x4){0.f, 0.f, 0.f, 0.f};

    for (int k0 = 0; k0 < K; k0 += 32) {
#pragma unroll
        for (int p = 0; p < 4; ++p) {
            int flat = p * 256 + tid;
            int ar = flat >> 3, aq = (flat & 7) * 4;
            int gk = k0 + aq;
            const float* src;
            if (TRISRC) {
                int row = row0 + ar;
                src = (gk < 512)  ? (A0 + (size_t)row * FEAT + gk)
                    : (gk < 1024) ? (A1 + (size_t)row * FEAT + (gk - 512))
                                  : (A2 + (size_t)row * FEAT + (gk - 1024));
            } else {
                src = A0 + (size_t)(row0 + ar) * lda + gk;
            }
            float4 v = *(const float4*)src;
            unsigned short h0,h1,h2,h3,q0,q1,q2,q3;
            split_bf16(v.x, h0, q0); split_bf16(v.y, h1, q1);
            split_bf16(v.z, h2, q2); split_bf16(v.w, h3, q3);
            *(short4*)&Ah[ar][aq] = make_short4((short)h0,(short)h1,(short)h2,(short)h3);
            *(short4*)&Al[ar][aq] = make_short4((short)q0,(short)q1,(short)q2,(short)q3);
        }
#pragma unroll
        for (int p = 0; p < 2; ++p) {
            int flat = p * 256 + tid;
            int br = flat >> 2, bq = (flat & 3) * 8;
            float4 vh = *(const float4*)(Bh + (size_t)(col0 + br) * ldb + k0 + bq);
            float4 vl = *(const float4*)(Bl + (size_t)(col0 + br) * ldb + k0 + bq);
            *(float4*)&Bhs[br][bq] = vh;
            *(float4*)&Bls[br][bq] = vl;
        }
        __syncthreads();

        bf16x8 ah[4], al4[4], bh[4], bl4[4];
#pragma unroll
        for (int mt = 0; mt < 4; ++mt) {
            ah[mt]  = *(const bf16x8*)&Ah[wm + mt * 16 + fr][fk];
            al4[mt] = *(const bf16x8*)&Al[wm + mt * 16 + fr][fk];
        }
#pragma unroll
        for (int nt = 0; nt < 4; ++nt) {
            bh[nt]  = *(const bf16x8*)&Bhs[wn + nt * 16 + fr][fk];
            bl4[nt] = *(const bf16x8*)&Bls[wn + nt * 16 + fr][fk];
        }
#pragma unroll
        for (int mt = 0; mt < 4; ++mt)
#pragma unroll
            for (int nt = 0; nt < 4; ++nt) {
                acc[mt][nt] = __builtin_amdgcn_mfma_f32_16x16x32_bf16(ah[mt],  bh[nt],  acc[mt][nt], 0, 0, 0);
                acc[mt][nt] = __builtin_amdgcn_mfma_f32_16x16x32_bf16(al4[mt], bh[nt],  acc[mt][nt], 0, 0, 0);
                acc[mt][nt] = __builtin_amdgcn_mfma_f32_16x16x32_bf16(ah[mt],  bl4[nt], acc[mt][nt], 0, 0, 0);
            }
        __syncthreads();
    }
#pragma unroll
    for (int mt = 0; mt < 4; ++mt) {
        int row = row0 + wm + mt * 16 + (l >> 4) * 4;
#pragma unroll
        for (int nt = 0; nt < 4; ++nt) {
            int col = col0 + wn + nt * 16 + fr;
            float bv = BIAS ? bias[col] : 0.0f;
#pragma unroll
            for (int j = 0; j < 4; ++j)
                C[(size_t)(row + j) * ldc + col] = acc[mt][nt][j] + bv;
        }
    }
}

// ================= MFMA GEMM: C = A @ B^T (+bias), pair-based A staging =================
// MODE 0: A = pair (Ahp/Alp), pure copy. K = span, stride lda.
// MODE 1: gates tri: k<512 f32 F split, k<1024 f32 R split, else pair Ahp/Alp. K=1536.
// MODE 2: gates tri: k<512 pair Fph/Fpl copy, k<1024 f32 R split, else pair Ahp/Alp. K=1536.
template<int BIAS, int MODE>
__global__ __launch_bounds__(256)
void mm_abt3(const unsigned short* __restrict__ Ahp, const unsigned short* __restrict__ Alp,
             const unsigned short* __restrict__ Fph, const unsigned short* __restrict__ Fpl,
             const float* __restrict__ F, const float* __restrict__ R,
             const unsigned short* __restrict__ Bh, const unsigned short* __restrict__ Bl,
             int lda, int ldb, float* __restrict__ C, int ldc,
             const float* __restrict__ bias, int K)
{
    __shared__ unsigned short Ah[128][40], Al[128][40], Bhs[128][40], Bls[128][40];
    const int tid = threadIdx.x;
    const int row0 = blockIdx.y * 128, col0 = blockIdx.x * 128;
    const int l = tid & 63;
    const int wm = ((tid >> 6) >> 1) * 64, wn = ((tid >> 6) & 1) * 64;
    const int fr = l & 15, fk = (l >> 4) * 8;

    f32x4 acc[4][4];
#pragma unroll
    for (int mt = 0; mt < 4; ++mt)
#pragma unroll
        for (int nt = 0; nt < 4; ++nt) acc[mt][nt] = (f32x4){0.f, 0.f, 0.f, 0.f};

    for (int k0 = 0; k0 < K; k0 += 32) {
        bool split_stage;
        const float* fsrc = nullptr;
        const unsigned short* ph = nullptr; const unsigned short* pl = nullptr;
        int coff = k0, cstride = lda;
        if (MODE == 0) {
            split_stage = false; ph = Ahp; pl = Alp;
        } else if (MODE == 1) {
            if (k0 < 512)       { split_stage = true;  fsrc = F; coff = k0;        cstride = FEAT; }
            else if (k0 < 1024) { split_stage = true;  fsrc = R; coff = k0 - 512;  cstride = FEAT; }
            else                { split_stage = false; ph = Ahp; pl = Alp; coff = k0 - 1024; cstride = FEAT; }
        } else { // MODE 2
            if (k0 < 512)       { split_stage = false; ph = Fph; pl = Fpl; coff = k0;        cstride = FEAT; }
            else if (k0 < 1024) { split_stage = true;  fsrc = R;           coff = k0 - 512;  cstride = FEAT; }
            else                { split_stage = false; ph = Ahp; pl = Alp; coff = k0 - 1024; cstride = FEAT; }
        }
        if (split_stage) {
#pragma unroll
            for (int p = 0; p < 4; ++p) {
                int flat = p * 256 + tid;
                int ar = flat >> 3, aq = (flat & 7) * 4;
                float4 v = *(const float4*)(fsrc + (size_t)(row0 + ar) * cstride + coff + aq);
                unsigned short h0,h1,h2,h3,q0,q1,q2,q3;
                split_bf16(v.x, h0, q0); split_bf16(v.y, h1, q1);
                split_bf16(v.z, h2, q2); split_bf16(v.w, h3, q3);
                *(short4*)&Ah[ar][aq] = make_short4((short)h0,(short)h1,(short)h2,(short)h3);
                *(short4*)&Al[ar][aq] = make_short4((short)q0,(short)q1,(short)q2,(short)q3);
            }
        } else {
#pragma unroll
            for (int p = 0; p < 2; ++p) {
                int flat = p * 256 + tid;
                int ar = flat >> 2, aq = (flat & 3) * 8;
                float4 vh = *(const float4*)(ph + (size_t)(row0 + ar) * cstride + coff + aq);
                float4 vl = *(const float4*)(pl + (size_t)(row0 + ar) * cstride + coff + aq);
                *(float4*)&Ah[ar][aq] = vh;
                *(float4*)&Al[ar][aq] = vl;
            }
        }
#pragma unroll
        for (int p = 0; p < 2; ++p) {
            int flat = p * 256 + tid;
            int br = flat >> 2, bq = (flat & 3) * 8;
            float4 vh = *(const float4*)(Bh + (size_t)(col0 + br) * ldb + k0 + bq);
            float4 vl = *(const float4*)(Bl + (size_t)(col0 + br) * ldb + k0 + bq);
            *(float4*)&Bhs[br][bq] = vh;
            *(float4*)&Bls[br][bq] = vl;
        }
        __syncthreads();

        bf16x8 ah[4], al4[4], bh[4], bl4[4];
#pragma unroll
        for (int mt = 0; mt < 4; ++mt) {
            ah[mt]  = *(const bf16x8*)&Ah[wm + mt * 16 + fr][fk];
            al4[mt] = *(const bf16x8*)&Al[wm + mt * 16 + fr][fk];
        }
#pragma unroll
        for (int nt = 0; nt < 4; ++nt) {
            bh[nt]  = *(const bf16x8*)&Bhs[wn + nt * 16 + fr][fk];
            bl4[nt] = *(const bf16x8*)&Bls[wn + nt * 16 + fr][fk];
        }
#pragma unroll
        for (int mt = 0; mt < 4; ++mt)
#pragma unroll
            for (int nt = 0; nt < 4; ++nt) {
                acc[mt][nt] = __builtin_amdgcn_mfma_f32_16x16x32_bf16(ah[mt],  bh[nt],  acc[mt][nt], 0, 0, 0);
                acc[mt][nt] = __builtin_amdgcn_mfma_f32_16x16x32_bf16(al4[mt], bh[nt],  acc[mt][nt], 0, 0, 0);
                acc[mt][nt] = __builtin_amdgcn_mfma_f32_16x16x32_bf16(ah[mt],  bl4[nt], acc[mt][nt], 0, 0, 0);
            }
        __syncthreads();
    }
#pragma unroll
    for (int mt = 0; mt < 4; ++mt) {
        int row = row0 + wm + mt * 16 + (l >> 4) * 4;
#pragma unroll
        for (int nt = 0; nt < 4; ++nt) {
            int col = col0 + wn + nt * 16 + fr;
            float bv = BIAS ? bias[col] : 0.0f;
#pragma unroll
            for (int j = 0; j < 4; ++j)
                C[(size_t)(row + j) * ldc + col] = acc[mt][nt][j] + bv;
        }
    }
}

// ================= MFMA GEMM: C (+)= exp(A) @ B, B pre-split bf16 pair =================
template<int ACC>
__global__ __launch_bounds__(256)
void mm_ab2(const float* __restrict__ A, int lda,
            const unsigned short* __restrict__ Bh, const unsigned short* __restrict__ Bl,
            int ldb, float* __restrict__ C, int ldc, int K,
            const float* __restrict__ cm, const float* __restrict__ ciz)
{
    __shared__ unsigned short Ah[128][40], Al[128][40], Bhs[128][40], Bls[128][40];
    const int tid = threadIdx.x;
    const int row0 = blockIdx.y * 128, col0 = blockIdx.x * 128;
    const int l = tid & 63;
    const int wm = ((tid >> 6) >> 1) * 64, wn = ((tid >> 6) & 1) * 64;
    const int fr = l & 15, fk = (l >> 4) * 8;

    f32x4 acc[4][4];
#pragma unroll
    for (int mt = 0; mt < 4; ++mt)
#pragma unroll
        for (int nt = 0; nt < 4; ++nt) acc[mt][nt] = (f32x4){0.f, 0.f, 0.f, 0.f};

    for (int k0 = 0; k0 < K; k0 += 32) {
#pragma unroll
        for (int p = 0; p < 4; ++p) {
            int flat = p * 256 + tid;
            int ar = flat >> 3, aq = (flat & 7) * 4;
            float4 v = *(const float4*)(A + (size_t)(row0 + ar) * lda + k0 + aq);
            int kk = k0 + aq;
            v.x = expf(v.x - cm[kk + 0]) * ciz[kk + 0];
            v.y = expf(v.y - cm[kk + 1]) * ciz[kk + 1];
            v.z = expf(v.z - cm[kk + 2]) * ciz[kk + 2];
            v.w = expf(v.w - cm[kk + 3]) * ciz[kk + 3];
            unsigned short h0,h1,h2,h3,q0,q1,q2,q3;
            split_bf16(v.x, h0, q0); split_bf16(v.y, h1, q1);
            split_bf16(v.z, h2, q2); split_bf16(v.w, h3, q3);
            *(short4*)&Ah[ar][aq] = make_short4((short)h0,(short)h1,(short)h2,(short)h3);
            *(short4*)&Al[ar][aq] = make_short4((short)q0,(short)q1,(short)q2,(short)q3);
        }
#pragma unroll
        for (int it2 = 0; it2 < 2; ++it2) {
            int item = it2 * 256 + tid;
            int q  = item >> 4;
            int kp = item & 15;
            const unsigned short* sh = Bh + (size_t)(k0 + 2 * kp) * ldb + col0 + q * 4;
            const unsigned short* sl = Bl + (size_t)(k0 + 2 * kp) * ldb + col0 + q * 4;
            ushort4 h0 = *(const ushort4*)sh;
            ushort4 h1 = *(const ushort4*)(sh + ldb);
            ushort4 l0 = *(const ushort4*)sl;
            ushort4 l1 = *(const ushort4*)(sl + ldb);
            unsigned short h0a[4] = {h0.x, h0.y, h0.z, h0.w};
            unsigned short h1a[4] = {h1.x, h1.y, h1.z, h1.w};
            unsigned short l0a[4] = {l0.x, l0.y, l0.z, l0.w};
            unsigned short l1a[4] = {l1.x, l1.y, l1.z, l1.w};
#pragma unroll
            for (int cc = 0; cc < 4; ++cc) {
                int col = q * 4 + cc;
                *(unsigned*)&Bhs[col][2 * kp] = (unsigned)h0a[cc] | ((unsigned)h1a[cc] << 16);
                *(unsigned*)&Bls[col][2 * kp] = (unsigned)l0a[cc] | ((unsigned)l1a[cc] << 16);
            }
        }
        __syncthreads();

        bf16x8 ah[4], al4[4], bh[4], bl4[4];
#pragma unroll
        for (int mt = 0; mt < 4; ++mt) {
            ah[mt]  = *(const bf16x8*)&Ah[wm + mt * 16 + fr][fk];
            al4[mt] = *(const bf16x8*)&Al[wm + mt * 16 + fr][fk];
        }
#pragma unroll
        for (int nt = 0; nt < 4; ++nt) {
            bh[nt]  = *(const bf16x8*)&Bhs[wn + nt * 16 + fr][fk];
            bl4[nt] = *(const bf16x8*)&Bls[wn + nt * 16 + fr][fk];
        }
#pragma unroll
        for (int mt = 0; mt < 4; ++mt)
#pragma unroll
            for (int nt = 0; nt < 4; ++nt) {
                acc[mt][nt] = __builtin_amdgcn_mfma_f32_16x16x32_bf16(ah[mt],  bh[nt],  acc[mt][nt], 0, 0, 0);
                acc[mt][nt] = __builtin_amdgcn_mfma_f32_16x16x32_bf16(al4[mt], bh[nt],  acc[mt][nt], 0, 0, 0);
                acc[mt][nt] = __builtin_amdgcn_mfma_f32_16x16x32_bf16(ah[mt],  bl4[nt], acc[mt][nt], 0, 0, 0);
            }
        __syncthreads();
    }
#pragma unroll
    for (int mt = 0; mt < 4; ++mt) {
        int row = row0 + wm + mt * 16 + (l >> 4) * 4;
#pragma unroll
        for (int nt = 0; nt < 4; ++nt) {
            int col = col0 + wn + nt * 16 + fr;
#pragma unroll
            for (int j = 0; j < 4; ++j) {
                size_t idx = (size_t)(row + j) * ldc + col;
                if (ACC) C[idx] += acc[mt][nt][j];
                else     C[idx]  = acc[mt][nt][j];
            }
        }
    }
}

// ---------------- f32 GEMM: C (+)= exp(A) @ B (tiny N=64 Y-GEMM), LOG fuses final log ----------------
template<int ACC, int LOG>
__global__ __launch_bounds__(256)
void gemm_ab(const float* __restrict__ A, int lda,
             const float* __restrict__ B, int ldb,
             float* __restrict__ C, int ldc, int K,
             const float* __restrict__ cm, const float* __restrict__ ciz)
{
    __shared__ float As[16][128];
    __shared__ float Bs[16][64];
    const int row0 = blockIdx.y * 128;
    const int col0 = blockIdx.x * 64;
    const int tid = threadIdx.x;
    const int tr = tid >> 4, tc = tid & 15;
    float acc[8][4];
#pragma unroll
    for (int i = 0; i < 8; ++i)
#pragma unroll
        for (int j = 0; j < 4; ++j) acc[i][j] = 0.0f;

    for (int k0 = 0; k0 < K; k0 += 16) {
#pragma unroll
        for (int p = tid; p < 512; p += 256) {
            int r = p >> 2, kq = (p & 3) * 4;
            float4 av = *(const float4*)(A + (size_t)(row0 + r) * lda + k0 + kq);
            int kk = k0 + kq;
            av.x = expf(av.x - cm[kk + 0]) * ciz[kk + 0];
            av.y = expf(av.y - cm[kk + 1]) * ciz[kk + 1];
            av.z = expf(av.z - cm[kk + 2]) * ciz[kk + 2];
            av.w = expf(av.w - cm[kk + 3]) * ciz[kk + 3];
            As[kq + 0][r] = av.x; As[kq + 1][r] = av.y; As[kq + 2][r] = av.z; As[kq + 3][r] = av.w;
        }
        {
            int kr = tid >> 4, cq = (tid & 15) * 4;
            float4 bv = *(const float4*)(B + (size_t)(k0 + kr) * ldb + col0 + cq);
            *(float4*)&Bs[kr][cq] = bv;
        }
        __syncthreads();
#pragma unroll
        for (int kk = 0; kk < 16; ++kk) {
            float4 a0 = *(const float4*)&As[kk][tr * 8];
            float4 a1 = *(const float4*)&As[kk][tr * 8 + 4];
            float4 b0 = *(const float4*)&Bs[kk][tc * 4];
            float a[8] = {a0.x, a0.y, a0.z, a0.w, a1.x, a1.y, a1.z, a1.w};
            float b[4] = {b0.x, b0.y, b0.z, b0.w};
#pragma unroll
            for (int i = 0; i < 8; ++i)
#pragma unroll
                for (int j = 0; j < 4; ++j) acc[i][j] += a[i] * b[j];
        }
        __syncthreads();
    }
#pragma unroll
    for (int i = 0; i < 8; ++i) {
        size_t idx = (size_t)(row0 + tr * 8 + i) * ldc + col0 + tc * 4;
#pragma unroll
        for (int j = 0; j < 4; ++j) {
            float v = ACC ? (C[idx + j] + acc[i][j]) : acc[i][j];
            C[idx + j] = LOG ? logf(v) : v;
        }
    }
}

// ---------------- persistent bidirectional LSTM ----------------
// r10 structure + distributed gate transcendentals: lanes 0-3 of each 16-lane
// group each evaluate one gate nonlinearity concurrently (uniform sigf path,
// tanh(x) = 2*sigf(2x)-1), 3 shfl_xor deliver to lane 0 -> shorter store tail.
__global__ __launch_bounds__(256, 1)
void lstm_persist(const float* __restrict__ Xf, const float* __restrict__ Xb,
                  const float* __restrict__ Wf, const float* __restrict__ Wb,
                  float* __restrict__ Hf, float* __restrict__ Hb)
{
    __shared__ float w_lds[64 * FEAT];   // 128 KB: row (e*4+g), col k
    __shared__ float hs[2][FEAT];

    const int bid = blockIdx.x;
    const int dir = bid >> 5;
    const int blk = bid & 31;
    const int tid = threadIdx.x;
    const float* W = dir ? Wb : Wf;
    const float* X = dir ? Xb : Xf;
    float* H = dir ? Hb : Hf;

    for (int idx = tid * 4; idx < 64 * FEAT; idx += 1024) {
        int row_ld = idx >> 9, col = idx & 511;
        int grow = (row_ld & 3) * FEAT + blk * 16 + (row_ld >> 2);
        float4 wv = *(const float4*)(W + (size_t)grow * FEAT + col);
        *(float4*)&w_lds[row_ld * FEAT + col] = wv;
    }
    __syncthreads();

    const int e = tid >> 4, l = tid & 15;
    const int hidx = blk * 16 + e;
    float c_reg = 0.0f;

    for (int t = 0; t < NS; ++t) {
        const int trow = dir ? (NS - 1 - t) : t;
        const float* Xrow = X + (size_t)trow * G4;
        // each of lanes 0-3 prefetches ITS gate's x term (hides under the poll)
        float xg = 0.f;
        if (l < 4) xg = Xrow[l * FEAT + hidx];
        float* hcur = hs[t & 1];
        if (t > 0) {
            const int prow = dir ? (trow + 1) : (trow - 1);
            const float* Hp = H + (size_t)prow * FEAT;
            float v0, v1;
            do {
                v0 = __hip_atomic_load(Hp + tid,       __ATOMIC_RELAXED, __HIP_MEMORY_SCOPE_AGENT);
                v1 = __hip_atomic_load(Hp + tid + 256, __ATOMIC_RELAXED, __HIP_MEMORY_SCOPE_AGENT);
            } while (v0 == SENT || v1 == SENT);
            hcur[tid] = v0; hcur[tid + 256] = v1;
        } else {
            hcur[tid] = 0.0f; hcur[tid + 256] = 0.0f;
        }
        __syncthreads();   // the only barrier per step (hs double-buffered)

        float dots[4];
#pragma unroll
        for (int g = 0; g < 4; ++g) {
            const float* w = &w_lds[(e * 4 + g) * FEAT];
            float s = 0.0f;
#pragma unroll
            for (int j = 0; j < 8; ++j) {
                int col = l * 4 + j * 64;
                float4 wv = *(const float4*)&w[col];
                float4 hv = *(const float4*)&hcur[col];
                s += wv.x * hv.x + wv.y * hv.y + wv.z * hv.z + wv.w * hv.w;
            }
#pragma unroll
            for (int off = 8; off >= 1; off >>= 1) s += __shfl_xor(s, off, 64);
            dots[g] = s;   // full sum lands in ALL 16 lanes of the group
        }
        // lanes 0-3 evaluate their gate's nonlinearity in parallel (uniform path):
        // l==2 (g gate): tanh(v) = 2*sigf(2v)-1 ; others: sigf(v)
        float vin = ((l & 3) == (unsigned)l && l < 4) ? (dots[l] + xg) : 0.0f;
        float varg = (l == 2) ? (2.0f * vin) : vin;
        float sg = sigf(varg);
        float vout = (l == 2) ? (2.0f * sg - 1.0f) : sg;
        float sf = __shfl_xor(vout, 1, 64);   // lane0 <- lane1 (forget)
        float tg = __shfl_xor(vout, 2, 64);   // lane0 <- lane2 (g, tanh'd)
        float so = __shfl_xor(vout, 3, 64);   // lane0 <- lane3 (output)
        if (l == 0) {
            float cn = sf * c_reg + vout * tg;          // vout = sigmoid(i)
            float tc2 = 2.0f * sigf(2.0f * cn) - 1.0f;  // tanh(cn)
            float hv = so * tc2;
            c_reg = cn;
            __hip_atomic_store(H + (size_t)trow * FEAT + hidx, hv,
                               __ATOMIC_RELAXED, __HIP_MEMORY_SCOPE_AGENT);
        }
    }
}

// ---------------- fused G assembly + row-normalize -> bf16 pairs ----------------
__global__ __launch_bounds__(256)
void gnorm_fuse(const float* __restrict__ S, const float* __restrict__ Hf,
                const float* __restrict__ Hb,
                unsigned short* __restrict__ Gh, unsigned short* __restrict__ Gl,
                unsigned short* __restrict__ Gnh, unsigned short* __restrict__ Gnl)
{
    const int row = blockIdx.x;
    const size_t base = (size_t)row * FEAT;
    const int tid = threadIdx.x;
    float v0 = S[base + tid]       + Hf[base + tid]       + Hb[base + tid];
    float v1 = S[base + tid + 256] + Hf[base + tid + 256] + Hb[base + tid + 256];
    float s = v0 * v0 + v1 * v1;
#pragma unroll
    for (int off = 32; off >= 1; off >>= 1) s += __shfl_xor(s, off, 64);
    __shared__ float red[4];
    if ((tid & 63) == 0) red[tid >> 6] = s;
    __syncthreads();
    float tot = red[0] + red[1] + red[2] + red[3];
    float inv = 1.0f / (sqrtf(tot) + 1e-5f);
    unsigned short h, l;
    split_bf16(v0, h, l);        Gh[base + tid] = h;        Gl[base + tid] = l;
    split_bf16(v1, h, l);        Gh[base + tid + 256] = h;  Gl[base + tid + 256] = l;
    split_bf16(v0 * inv, h, l);  Gnh[base + tid] = h;       Gnl[base + tid] = l;
    split_bf16(v1 * inv, h, l);  Gnh[base + tid + 256] = h; Gnl[base + tid + 256] = l;
}

// ---------------- column softmax stats over a [NQ x slab] buffer ----------------
__global__ __launch_bounds__(256)
void colstats_partial(const float* __restrict__ A, float* __restrict__ pm,
                      float* __restrict__ pz, int slab)
{
    const int col = blockIdx.x * 256 + threadIdx.x;
    const int r0 = blockIdx.y * 128;
    float m = -3.0e38f, z = 0.0f;
    for (int r = 0; r < 128; ++r) {
        float v = A[(size_t)(r0 + r) * slab + col];
        if (v > m) { z = z * expf(m - v) + 1.0f; m = v; }
        else       { z += expf(v - m); }
    }
    pm[(size_t)blockIdx.y * slab + col] = m;
    pz[(size_t)blockIdx.y * slab + col] = z;
}

__global__ __launch_bounds__(256)
void colstats_combine(const float* __restrict__ pm, const float* __restrict__ pz,
                      float* __restrict__ cm, float* __restrict__ ciz, int slab)
{
    const int col = blockIdx.x * 256 + threadIdx.x;
    float m = -3.0e38f;
    for (int p = 0; p < 64; ++p) m = fmaxf(m, pm[(size_t)p * slab + col]);
    float z = 0.0f;
    for (int p = 0; p < 64; ++p) z += pz[(size_t)p * slab + col] * expf(pm[(size_t)p * slab + col] - m);
    cm[col] = m;
    ciz[col] = 1.0f / z;
}

// ---------------- FCE cell on one k-slice; writes h as bf16 hi/lo pair ----------------
__global__ void cell_slice(const float* __restrict__ gslab, float* __restrict__ cst,
                           unsigned short* __restrict__ hh, unsigned short* __restrict__ hl,
                           const float* __restrict__ f,
                           int k0, int ldg, int kshift)
{
    int i = blockIdx.x * blockDim.x + threadIdx.x;
    const int st = gridDim.x * blockDim.x;
    const int n = NQ << kshift;
    const int kmask = (1 << kshift) - 1;
    for (; i < n; i += st) {
        int q = i >> kshift, kk = i & kmask;
        float4 g = *(const float4*)(gslab + (size_t)q * ldg + kk * 4);
        int idx = q * FEAT + k0 + kk;
        float cold = cst[idx];
        float cn = sigf(g.y) * cold + sigf(g.x) * tanhf(g.z);
        float hn = sigf(g.w) * tanhf(cn) + f[idx];
        cst[idx] = cn;
        unsigned short ph, pl;
        split_bf16(hn, ph, pl);
        hh[idx] = ph; hl[idx] = pl;
    }
}

// ---------------- launch ----------------
extern "C" void kernel_launch(void* const* d_in, const int* in_sizes, int n_in,
                              void* d_out, int out_size, void* d_ws, size_t ws_size,
                              hipStream_t stream)
{
    (void)in_sizes; (void)n_in; (void)out_size;
    const float* S     = (const float*)d_in[0];
    const float* f     = (const float*)d_in[1];
    const float* Y     = (const float*)d_in[2];
    const float* Wf_ih = (const float*)d_in[3];
    const float* Wf_hh = (const float*)d_in[4];
    const float* bf    = (const float*)d_in[5];
    const float* Wb_ih = (const float*)d_in[6];
    const float* Wb_hh = (const float*)d_in[7];
    const float* bb    = (const float*)d_in[8];
    const float* Wc_ih = (const float*)d_in[9];
    const float* Wc_hh = (const float*)d_in[10];
    const float* bc    = (const float*)d_in[11];
    float* out = (float*)d_out;

    // footprint tiers: slab1024+fpair=141MB, slab1024=125MB, slab512=109MB
    const bool big    = ws_size >= (size_t)142 * 1024 * 1024;
    const bool mid    = ws_size >= (size_t)126 * 1024 * 1024;
    const int  slab   = (big || mid) ? 1024 : 512;
    const bool fpair  = big;
    const int nslab  = NS / slab;
    const int nslice = 2048 / slab;
    const int kwidth = slab / 4;
    const int kshift = (slab == 1024) ? 8 : 7;

    float* ws = (float*)d_ws;
    // region 0: 16M floats — phase A/B: Xf|Xb ; phase C: r|cst|h-pair0|h-pair1
    float* Xf   = ws;
    float* Xb   = ws + (size_t)8 * 1024 * 1024;
    float* r    = ws;
    float* cst  = ws + (size_t)4 * 1024 * 1024;
    unsigned short* p0h = (unsigned short*)(ws + (size_t)8 * 1024 * 1024);
    unsigned short* p0l = (unsigned short*)(ws + (size_t)10 * 1024 * 1024);
    unsigned short* p1h = (unsigned short*)(ws + (size_t)12 * 1024 * 1024);
    unsigned short* p1l = (unsigned short*)(ws + (size_t)14 * 1024 * 1024);
    size_t off  = (size_t)16 * 1024 * 1024;
    auto alloc = [&](size_t n) { float* p = ws + off; off += n; return p; };
    float* Pslab = alloc((size_t)NQ * slab);
    unsigned short* Gh  = (unsigned short*)alloc(1024 * 1024);
    unsigned short* Gl  = (unsigned short*)alloc(1024 * 1024);
    unsigned short* Gnh = (unsigned short*)alloc(1024 * 1024);
    unsigned short* Gnl = (unsigned short*)alloc(1024 * 1024);
    unsigned short* Wph = (unsigned short*)alloc(1536 * 1024);
    unsigned short* Wpl = (unsigned short*)alloc(1536 * 1024);
    float* bpack = alloc(G4);
    float* pm    = alloc((size_t)64 * 1024);
    float* pz    = alloc((size_t)64 * 1024);
    float* cm    = alloc(1024);
    float* ciz   = alloc(1024);
    unsigned short* fh = nullptr; unsigned short* fl = nullptr;
    if (fpair) {
        fh = (unsigned short*)alloc(2 * 1024 * 1024);   // NQ*FEAT shorts
        fl = (unsigned short*)alloc(2 * 1024 * 1024);
    }

    float* Hf = Pslab;
    float* Hb = Pslab + (size_t)2 * 1024 * 1024;

    const dim3 B256(256);

    // ---- Phase A: Xf = S@Wf_ih^T+bf, Xb = S@Wb_ih^T+bb ----
    mm_abt_f32<1><<<dim3(16, 32), B256, 0, stream>>>(S, Wf_ih, FEAT, FEAT, Xf, G4, bf, FEAT);
    mm_abt_f32<1><<<dim3(16, 32), B256, 0, stream>>>(S, Wb_ih, FEAT, FEAT, Xb, G4, bb, FEAT);

    // ---- Phase B: persistent bidirectional LSTM ----
    kfill<<<dim3(2048), B256, 0, stream>>>(Pslab, SENT, 4 * 1024 * 1024);  // Hf+Hb sentinel
    lstm_persist<<<dim3(64), B256, 0, stream>>>(Xf, Xb, Wf_hh, Wb_hh, Hf, Hb);
    gnorm_fuse<<<dim3(NS), B256, 0, stream>>>(S, Hf, Hb, Gh, Gl, Gnh, Gnl);

    // ---- Phase C prep ----
    pack_w<<<dim3(2048), B256, 0, stream>>>(Wph, Wpl, bpack, Wc_ih, Wc_hh, bc);
    kzero<<<dim3(1024), B256, 0, stream>>>(cst, NQ * FEAT);     // c = 0
    if (fpair)
        split_arr<<<dim3(2048), B256, 0, stream>>>(f, fh, fl, NQ * FEAT);

    // ---- Phase C: K=3 FCE iterations (h0 = f) ----
    for (int it = 0; it < 3; ++it) {
        const unsigned short* hch = (it == 1) ? p0h : p1h;   // iter2 reads p1
        const unsigned short* hcl = (it == 1) ? p0l : p1l;
        unsigned short* hxh = (it == 1) ? p1h : p0h;         // iter0->p0, iter1->p1, iter2->p0
        unsigned short* hxl = (it == 1) ? p1l : p0l;
        for (int sb = 0; sb < nslab; ++sb) {
            const unsigned short* Gsh = Gh + (size_t)sb * slab * FEAT;
            const unsigned short* Gsl = Gl + (size_t)sb * slab * FEAT;
            if (it == 0) {
                if (fpair)
                    mm_abt3<0,0><<<dim3(slab / 128, 64), B256, 0, stream>>>(fh, fl, nullptr, nullptr, nullptr, nullptr,
                                                                            Gsh, Gsl, FEAT, FEAT, Pslab, slab, nullptr, FEAT);
                else
                    mm_abt2<0,0><<<dim3(slab / 128, 64), B256, 0, stream>>>(f, nullptr, nullptr, Gsh, Gsl,
                                                                            FEAT, FEAT, Pslab, slab, nullptr, FEAT);
            } else {
                mm_abt3<0,0><<<dim3(slab / 128, 64), B256, 0, stream>>>(hch, hcl, nullptr, nullptr, nullptr, nullptr,
                                                                        Gsh, Gsl, FEAT, FEAT, Pslab, slab, nullptr, FEAT);
            }
            colstats_partial<<<dim3(slab / 256, 64), B256, 0, stream>>>(Pslab, pm, pz, slab);
            colstats_combine<<<dim3(slab / 256), B256, 0, stream>>>(pm, pz, cm, ciz, slab);
            if (sb == 0) mm_ab2<0><<<dim3(4, 64), B256, 0, stream>>>(Pslab, slab, Gsh, Gsl, FEAT, r, FEAT, slab, cm, ciz);
            else         mm_ab2<1><<<dim3(4, 64), B256, 0, stream>>>(Pslab, slab, Gsh, Gsl, FEAT, r, FEAT, slab, cm, ciz);
        }
        for (int sl = 0; sl < nslice; ++sl) {
            const unsigned short* Wsh = Wph + (size_t)sl * slab * 1536;
            const unsigned short* Wsl = Wpl + (size_t)sl * slab * 1536;
            if (fpair) {
                const unsigned short* hhp = (it == 0) ? fh : hch;
                const unsigned short* hlp = (it == 0) ? fl : hcl;
                mm_abt3<1,2><<<dim3(slab / 128, 64), B256, 0, stream>>>(hhp, hlp, fh, fl, nullptr, r,
                                                                        Wsh, Wsl, FEAT, 1536, Pslab, slab, bpack + sl * slab, 1536);
            } else {
                if (it == 0)
                    mm_abt2<1,1><<<dim3(slab / 128, 64), B256, 0, stream>>>(f, r, f, Wsh, Wsl,
                                                                            FEAT, 1536, Pslab, slab, bpack + sl * slab, 1536);
                else
                    mm_abt3<1,1><<<dim3(slab / 128, 64), B256, 0, stream>>>(hch, hcl, nullptr, nullptr, f, r,
                                                                            Wsh, Wsl, FEAT, 1536, Pslab, slab, bpack + sl * slab, 1536);
            }
            cell_slice<<<dim3(2048), B256, 0, stream>>>(Pslab, cst, hxh, hxl, f, sl * kwidth, slab, kshift);
        }
    }

    // ---- Phase D: out = log(softmax_col(h @ Gn^T) @ Y); h = pair0 (after iter 2) ----
    for (int sb = 0; sb < nslab; ++sb) {
        const unsigned short* Gsh = Gnh + (size_t)sb * slab * FEAT;
        const unsigned short* Gsl = Gnl + (size_t)sb * slab * FEAT;
        mm_abt3<0,0><<<dim3(slab / 128, 64), B256, 0, stream>>>(p0h, p0l, nullptr, nullptr, nullptr, nullptr,
                                                                Gsh, Gsl, FEAT, FEAT, Pslab, slab, nullptr, FEAT);
        colstats_partial<<<dim3(slab / 256, 64), B256, 0, stream>>>(Pslab, pm, pz, slab);
        colstats_combine<<<dim3(slab / 256), B256, 0, stream>>>(pm, pz, cm, ciz, slab);
        const float* Ys = Y + (size_t)sb * slab * NC;
        if (nslab == 1)           gemm_ab<0,1><<<dim3(1, 64), B256, 0, stream>>>(Pslab, slab, Ys, NC, out, NC, slab, cm, ciz);
        else if (sb == 0)         gemm_ab<0,0><<<dim3(1, 64), B256, 0, stream>>>(Pslab, slab, Ys, NC, out, NC, slab, cm, ciz);
        else if (sb == nslab - 1) gemm_ab<1,1><<<dim3(1, 64), B256, 0, stream>>>(Pslab, slab, Ys, NC, out, NC, slab, cm, ciz);
        else                      gemm_ab<1,0><<<dim3(1, 64), B256, 0, stream>>>(Pslab, slab, Ys, NC, out, NC, slab, cm, ciz);
    }
}

// Round 14
// 12513.795 us; speedup vs baseline: 1.2458x; 1.2458x over previous
//
#include <hip/hip_runtime.h>
#include <math.h>

#define FEAT 512
#define NS   4096
#define NQ   8192
#define NC   64
#define G4   2048   // 4*FEAT
#define SENT 1.0e30f

using bf16x8 = __attribute__((ext_vector_type(8))) short;
using f32x4  = __attribute__((ext_vector_type(4))) float;

__device__ __forceinline__ float sigf(float x) { return 1.0f / (1.0f + expf(-x)); }

// RNE f32 -> bf16 hi, residual -> bf16 lo
__device__ __forceinline__ void split_bf16(float x, unsigned short& hi, unsigned short& lo) {
    unsigned u = __float_as_uint(x);
    unsigned r = u + 0x7FFFu + ((u >> 16) & 1u);
    hi = (unsigned short)(r >> 16);
    float res = x - __uint_as_float((unsigned)hi << 16);
    unsigned u2 = __float_as_uint(res);
    unsigned r2 = u2 + 0x7FFFu + ((u2 >> 16) & 1u);
    lo = (unsigned short)(r2 >> 16);
}

// ---------------- small utility kernels ----------------
__global__ void kzero(float* __restrict__ dst, int n) {
    int i = blockIdx.x * blockDim.x + threadIdx.x;
    int st = gridDim.x * blockDim.x;
    for (; i < n; i += st) dst[i] = 0.0f;
}

__global__ void kfill(float* __restrict__ dst, float v, int n) {
    int i = blockIdx.x * blockDim.x + threadIdx.x;
    int st = gridDim.x * blockDim.x;
    for (; i < n; i += st) dst[i] = v;
}

__global__ void split_arr(const float* __restrict__ in, unsigned short* __restrict__ oh,
                          unsigned short* __restrict__ ol, int n) {
    int i = blockIdx.x * blockDim.x + threadIdx.x;
    int st = gridDim.x * blockDim.x;
    for (; i < n; i += st) {
        unsigned short h, l;
        split_bf16(in[i], h, l);
        oh[i] = h; ol[i] = l;
    }
}

// pack Wpack pair: [k*4+g][0:1536] = [Wc_ih[g*512+k][0:1024] | Wc_hh[g*512+k][0:512]]
__global__ void pack_w(unsigned short* __restrict__ Wph, unsigned short* __restrict__ Wpl,
                       float* __restrict__ bpack,
                       const float* __restrict__ Wc_ih, const float* __restrict__ Wc_hh,
                       const float* __restrict__ bc) {
    int i = blockIdx.x * blockDim.x + threadIdx.x;
    int st = gridDim.x * blockDim.x;
    const int n = G4 * 1536;
    for (; i < n; i += st) {
        int R = i / 1536, j = i - R * 1536;
        int k = R >> 2, g = R & 3;
        int row2 = g * FEAT + k;
        float v = (j < 1024) ? Wc_ih[(size_t)row2 * 1024 + j]
                             : Wc_hh[(size_t)row2 * FEAT + (j - 1024)];
        unsigned short h, l;
        split_bf16(v, h, l);
        Wph[i] = h; Wpl[i] = l;
        if (j == 0) bpack[R] = bc[row2];
    }
}

// ================= f32-staged MFMA GEMM: C = A @ B^T (+bias) — Phase A =================
template<int BIAS>
__global__ __launch_bounds__(256)
void mm_abt_f32(const float* __restrict__ A0, const float* __restrict__ B,
                int lda, int ldb, float* __restrict__ C, int ldc,
                const float* __restrict__ bias, int K)
{
    __shared__ unsigned short Ah[128][40], Al[128][40], Bh[128][40], Bl[128][40];
    const int tid = threadIdx.x;
    const int row0 = blockIdx.y * 128, col0 = blockIdx.x * 128;
    const int l = tid & 63;
    const int wm = ((tid >> 6) >> 1) * 64, wn = ((tid >> 6) & 1) * 64;
    const int fr = l & 15, fk = (l >> 4) * 8;

    f32x4 acc[4][4];
#pragma unroll
    for (int mt = 0; mt < 4; ++mt)
#pragma unroll
        for (int nt = 0; nt < 4; ++nt) acc[mt][nt] = (f32x4){0.f, 0.f, 0.f, 0.f};

    for (int k0 = 0; k0 < K; k0 += 32) {
#pragma unroll
        for (int p = 0; p < 4; ++p) {
            int flat = p * 256 + tid;
            int ar = flat >> 3, aq = (flat & 7) * 4;
            float4 v = *(const float4*)(A0 + (size_t)(row0 + ar) * lda + k0 + aq);
            unsigned short h0,h1,h2,h3,q0,q1,q2,q3;
            split_bf16(v.x, h0, q0); split_bf16(v.y, h1, q1);
            split_bf16(v.z, h2, q2); split_bf16(v.w, h3, q3);
            *(short4*)&Ah[ar][aq] = make_short4((short)h0,(short)h1,(short)h2,(short)h3);
            *(short4*)&Al[ar][aq] = make_short4((short)q0,(short)q1,(short)q2,(short)q3);
        }
#pragma unroll
        for (int p = 0; p < 4; ++p) {
            int flat = p * 256 + tid;
            int br = flat >> 3, bq = (flat & 7) * 4;
            float4 v = *(const float4*)(B + (size_t)(col0 + br) * ldb + k0 + bq);
            unsigned short h0,h1,h2,h3,q0,q1,q2,q3;
            split_bf16(v.x, h0, q0); split_bf16(v.y, h1, q1);
            split_bf16(v.z, h2, q2); split_bf16(v.w, h3, q3);
            *(short4*)&Bh[br][bq] = make_short4((short)h0,(short)h1,(short)h2,(short)h3);
            *(short4*)&Bl[br][bq] = make_short4((short)q0,(short)q1,(short)q2,(short)q3);
        }
        __syncthreads();

        bf16x8 ah[4], al4[4], bh[4], bl4[4];
#pragma unroll
        for (int mt = 0; mt < 4; ++mt) {
            ah[mt]  = *(const bf16x8*)&Ah[wm + mt * 16 + fr][fk];
            al4[mt] = *(const bf16x8*)&Al[wm + mt * 16 + fr][fk];
        }
#pragma unroll
        for (int nt = 0; nt < 4; ++nt) {
            bh[nt]  = *(const bf16x8*)&Bh[wn + nt * 16 + fr][fk];
            bl4[nt] = *(const bf16x8*)&Bl[wn + nt * 16 + fr][fk];
        }
#pragma unroll
        for (int mt = 0; mt < 4; ++mt)
#pragma unroll
            for (int nt = 0; nt < 4; ++nt) {
                acc[mt][nt] = __builtin_amdgcn_mfma_f32_16x16x32_bf16(ah[mt],  bh[nt],  acc[mt][nt], 0, 0, 0);
                acc[mt][nt] = __builtin_amdgcn_mfma_f32_16x16x32_bf16(al4[mt], bh[nt],  acc[mt][nt], 0, 0, 0);
                acc[mt][nt] = __builtin_amdgcn_mfma_f32_16x16x32_bf16(ah[mt],  bl4[nt], acc[mt][nt], 0, 0, 0);
            }
        __syncthreads();
    }
#pragma unroll
    for (int mt = 0; mt < 4; ++mt) {
        int row = row0 + wm + mt * 16 + (l >> 4) * 4;
#pragma unroll
        for (int nt = 0; nt < 4; ++nt) {
            int col = col0 + wn + nt * 16 + fr;
            float bv = BIAS ? bias[col] : 0.0f;
#pragma unroll
            for (int j = 0; j < 4; ++j)
                C[(size_t)(row + j) * ldc + col] = acc[mt][nt][j] + bv;
        }
    }
}

// ================= MFMA GEMM: C = A @ B^T (+bias), A f32 on-the-fly, B pair =================
// TRISRC: A = [A0|A1|A2] f32 concat along K (512 each). (fallback path)
template<int BIAS, int TRISRC>
__global__ __launch_bounds__(256)
void mm_abt2(const float* __restrict__ A0, const float* __restrict__ A1,
             const float* __restrict__ A2,
             const unsigned short* __restrict__ Bh, const unsigned short* __restrict__ Bl,
             int lda, int ldb, float* __restrict__ C, int ldc,
             const float* __restrict__ bias, int K)
{
    __shared__ unsigned short Ah[128][40], Al[128][40], Bhs[128][40], Bls[128][40];
    const int tid = threadIdx.x;
    const int row0 = blockIdx.y * 128, col0 = blockIdx.x * 128;
    const int l = tid & 63;
    const int wm = ((tid >> 6) >> 1) * 64, wn = ((tid >> 6) & 1) * 64;
    const int fr = l & 15, fk = (l >> 4) * 8;

    f32x4 acc[4][4];
#pragma unroll
    for (int mt = 0; mt < 4; ++mt)
#pragma unroll
        for (int nt = 0; nt < 4; ++nt) acc[mt][nt] = (f32x4){0.f, 0.f, 0.f, 0.f};

    for (int k0 = 0; k0 < K; k0 += 32) {
#pragma unroll
        for (int p = 0; p < 4; ++p) {
            int flat = p * 256 + tid;
            int ar = flat >> 3, aq = (flat & 7) * 4;
            int gk = k0 + aq;
            const float* src;
            if (TRISRC) {
                int row = row0 + ar;
                src = (gk < 512)  ? (A0 + (size_t)row * FEAT + gk)
                    : (gk < 1024) ? (A1 + (size_t)row * FEAT + (gk - 512))
                                  : (A2 + (size_t)row * FEAT + (gk - 1024));
            } else {
                src = A0 + (size_t)(row0 + ar) * lda + gk;
            }
            float4 v = *(const float4*)src;
            unsigned short h0,h1,h2,h3,q0,q1,q2,q3;
            split_bf16(v.x, h0, q0); split_bf16(v.y, h1, q1);
            split_bf16(v.z, h2, q2); split_bf16(v.w, h3, q3);
            *(short4*)&Ah[ar][aq] = make_short4((short)h0,(short)h1,(short)h2,(short)h3);
            *(short4*)&Al[ar][aq] = make_short4((short)q0,(short)q1,(short)q2,(short)q3);
        }
#pragma unroll
        for (int p = 0; p < 2; ++p) {
            int flat = p * 256 + tid;
            int br = flat >> 2, bq = (flat & 3) * 8;
            float4 vh = *(const float4*)(Bh + (size_t)(col0 + br) * ldb + k0 + bq);
            float4 vl = *(const float4*)(Bl + (size_t)(col0 + br) * ldb + k0 + bq);
            *(float4*)&Bhs[br][bq] = vh;
            *(float4*)&Bls[br][bq] = vl;
        }
        __syncthreads();

        bf16x8 ah[4], al4[4], bh[4], bl4[4];
#pragma unroll
        for (int mt = 0; mt < 4; ++mt) {
            ah[mt]  = *(const bf16x8*)&Ah[wm + mt * 16 + fr][fk];
            al4[mt] = *(const bf16x8*)&Al[wm + mt * 16 + fr][fk];
        }
#pragma unroll
        for (int nt = 0; nt < 4; ++nt) {
            bh[nt]  = *(const bf16x8*)&Bhs[wn + nt * 16 + fr][fk];
            bl4[nt] = *(const bf16x8*)&Bls[wn + nt * 16 + fr][fk];
        }
#pragma unroll
        for (int mt = 0; mt < 4; ++mt)
#pragma unroll
            for (int nt = 0; nt < 4; ++nt) {
                acc[mt][nt] = __builtin_amdgcn_mfma_f32_16x16x32_bf16(ah[mt],  bh[nt],  acc[mt][nt], 0, 0, 0);
                acc[mt][nt] = __builtin_amdgcn_mfma_f32_16x16x32_bf16(al4[mt], bh[nt],  acc[mt][nt], 0, 0, 0);
                acc[mt][nt] = __builtin_amdgcn_mfma_f32_16x16x32_bf16(ah[mt],  bl4[nt], acc[mt][nt], 0, 0, 0);
            }
        __syncthreads();
    }
#pragma unroll
    for (int mt = 0; mt < 4; ++mt) {
        int row = row0 + wm + mt * 16 + (l >> 4) * 4;
#pragma unroll
        for (int nt = 0; nt < 4; ++nt) {
            int col = col0 + wn + nt * 16 + fr;
            float bv = BIAS ? bias[col] : 0.0f;
#pragma unroll
            for (int j = 0; j < 4; ++j)
                C[(size_t)(row + j) * ldc + col] = acc[mt][nt][j] + bv;
        }
    }
}

// ================= MFMA GEMM: C = A @ B^T (+bias), pair-based A staging =================
// MODE 0: A = pair (Ahp/Alp), pure copy. K = span, stride lda.
// MODE 1: gates tri: k<512 f32 F split, k<1024 f32 R split, else pair Ahp/Alp. K=1536.
// MODE 2: gates tri: k<512 pair Fph/Fpl copy, k<1024 f32 R split, else pair Ahp/Alp. K=1536.
template<int BIAS, int MODE>
__global__ __launch_bounds__(256)
void mm_abt3(const unsigned short* __restrict__ Ahp, const unsigned short* __restrict__ Alp,
             const unsigned short* __restrict__ Fph, const unsigned short* __restrict__ Fpl,
             const float* __restrict__ F, const float* __restrict__ R,
             const unsigned short* __restrict__ Bh, const unsigned short* __restrict__ Bl,
             int lda, int ldb, float* __restrict__ C, int ldc,
             const float* __restrict__ bias, int K)
{
    __shared__ unsigned short Ah[128][40], Al[128][40], Bhs[128][40], Bls[128][40];
    const int tid = threadIdx.x;
    const int row0 = blockIdx.y * 128, col0 = blockIdx.x * 128;
    const int l = tid & 63;
    const int wm = ((tid >> 6) >> 1) * 64, wn = ((tid >> 6) & 1) * 64;
    const int fr = l & 15, fk = (l >> 4) * 8;

    f32x4 acc[4][4];
#pragma unroll
    for (int mt = 0; mt < 4; ++mt)
#pragma unroll
        for (int nt = 0; nt < 4; ++nt) acc[mt][nt] = (f32x4){0.f, 0.f, 0.f, 0.f};

    for (int k0 = 0; k0 < K; k0 += 32) {
        bool split_stage;
        const float* fsrc = nullptr;
        const unsigned short* ph = nullptr; const unsigned short* pl = nullptr;
        int coff = k0, cstride = lda;
        if (MODE == 0) {
            split_stage = false; ph = Ahp; pl = Alp;
        } else if (MODE == 1) {
            if (k0 < 512)       { split_stage = true;  fsrc = F; coff = k0;        cstride = FEAT; }
            else if (k0 < 1024) { split_stage = true;  fsrc = R; coff = k0 - 512;  cstride = FEAT; }
            else                { split_stage = false; ph = Ahp; pl = Alp; coff = k0 - 1024; cstride = FEAT; }
        } else { // MODE 2
            if (k0 < 512)       { split_stage = false; ph = Fph; pl = Fpl; coff = k0;        cstride = FEAT; }
            else if (k0 < 1024) { split_stage = true;  fsrc = R;           coff = k0 - 512;  cstride = FEAT; }
            else                { split_stage = false; ph = Ahp; pl = Alp; coff = k0 - 1024; cstride = FEAT; }
        }
        if (split_stage) {
#pragma unroll
            for (int p = 0; p < 4; ++p) {
                int flat = p * 256 + tid;
                int ar = flat >> 3, aq = (flat & 7) * 4;
                float4 v = *(const float4*)(fsrc + (size_t)(row0 + ar) * cstride + coff + aq);
                unsigned short h0,h1,h2,h3,q0,q1,q2,q3;
                split_bf16(v.x, h0, q0); split_bf16(v.y, h1, q1);
                split_bf16(v.z, h2, q2); split_bf16(v.w, h3, q3);
                *(short4*)&Ah[ar][aq] = make_short4((short)h0,(short)h1,(short)h2,(short)h3);
                *(short4*)&Al[ar][aq] = make_short4((short)q0,(short)q1,(short)q2,(short)q3);
            }
        } else {
#pragma unroll
            for (int p = 0; p < 2; ++p) {
                int flat = p * 256 + tid;
                int ar = flat >> 2, aq = (flat & 3) * 8;
                float4 vh = *(const float4*)(ph + (size_t)(row0 + ar) * cstride + coff + aq);
                float4 vl = *(const float4*)(pl + (size_t)(row0 + ar) * cstride + coff + aq);
                *(float4*)&Ah[ar][aq] = vh;
                *(float4*)&Al[ar][aq] = vl;
            }
        }
#pragma unroll
        for (int p = 0; p < 2; ++p) {
            int flat = p * 256 + tid;
            int br = flat >> 2, bq = (flat & 3) * 8;
            float4 vh = *(const float4*)(Bh + (size_t)(col0 + br) * ldb + k0 + bq);
            float4 vl = *(const float4*)(Bl + (size_t)(col0 + br) * ldb + k0 + bq);
            *(float4*)&Bhs[br][bq] = vh;
            *(float4*)&Bls[br][bq] = vl;
        }
        __syncthreads();

        bf16x8 ah[4], al4[4], bh[4], bl4[4];
#pragma unroll
        for (int mt = 0; mt < 4; ++mt) {
            ah[mt]  = *(const bf16x8*)&Ah[wm + mt * 16 + fr][fk];
            al4[mt] = *(const bf16x8*)&Al[wm + mt * 16 + fr][fk];
        }
#pragma unroll
        for (int nt = 0; nt < 4; ++nt) {
            bh[nt]  = *(const bf16x8*)&Bhs[wn + nt * 16 + fr][fk];
            bl4[nt] = *(const bf16x8*)&Bls[wn + nt * 16 + fr][fk];
        }
#pragma unroll
        for (int mt = 0; mt < 4; ++mt)
#pragma unroll
            for (int nt = 0; nt < 4; ++nt) {
                acc[mt][nt] = __builtin_amdgcn_mfma_f32_16x16x32_bf16(ah[mt],  bh[nt],  acc[mt][nt], 0, 0, 0);
                acc[mt][nt] = __builtin_amdgcn_mfma_f32_16x16x32_bf16(al4[mt], bh[nt],  acc[mt][nt], 0, 0, 0);
                acc[mt][nt] = __builtin_amdgcn_mfma_f32_16x16x32_bf16(ah[mt],  bl4[nt], acc[mt][nt], 0, 0, 0);
            }
        __syncthreads();
    }
#pragma unroll
    for (int mt = 0; mt < 4; ++mt) {
        int row = row0 + wm + mt * 16 + (l >> 4) * 4;
#pragma unroll
        for (int nt = 0; nt < 4; ++nt) {
            int col = col0 + wn + nt * 16 + fr;
            float bv = BIAS ? bias[col] : 0.0f;
#pragma unroll
            for (int j = 0; j < 4; ++j)
                C[(size_t)(row + j) * ldc + col] = acc[mt][nt][j] + bv;
        }
    }
}

// ================= MFMA GEMM: C (+)= exp(A) @ B, B pre-split bf16 pair =================
template<int ACC>
__global__ __launch_bounds__(256)
void mm_ab2(const float* __restrict__ A, int lda,
            const unsigned short* __restrict__ Bh, const unsigned short* __restrict__ Bl,
            int ldb, float* __restrict__ C, int ldc, int K,
            const float* __restrict__ cm, const float* __restrict__ ciz)
{
    __shared__ unsigned short Ah[128][40], Al[128][40], Bhs[128][40], Bls[128][40];
    const int tid = threadIdx.x;
    const int row0 = blockIdx.y * 128, col0 = blockIdx.x * 128;
    const int l = tid & 63;
    const int wm = ((tid >> 6) >> 1) * 64, wn = ((tid >> 6) & 1) * 64;
    const int fr = l & 15, fk = (l >> 4) * 8;

    f32x4 acc[4][4];
#pragma unroll
    for (int mt = 0; mt < 4; ++mt)
#pragma unroll
        for (int nt = 0; nt < 4; ++nt) acc[mt][nt] = (f32x4){0.f, 0.f, 0.f, 0.f};

    for (int k0 = 0; k0 < K; k0 += 32) {
#pragma unroll
        for (int p = 0; p < 4; ++p) {
            int flat = p * 256 + tid;
            int ar = flat >> 3, aq = (flat & 7) * 4;
            float4 v = *(const float4*)(A + (size_t)(row0 + ar) * lda + k0 + aq);
            int kk = k0 + aq;
            v.x = expf(v.x - cm[kk + 0]) * ciz[kk + 0];
            v.y = expf(v.y - cm[kk + 1]) * ciz[kk + 1];
            v.z = expf(v.z - cm[kk + 2]) * ciz[kk + 2];
            v.w = expf(v.w - cm[kk + 3]) * ciz[kk + 3];
            unsigned short h0,h1,h2,h3,q0,q1,q2,q3;
            split_bf16(v.x, h0, q0); split_bf16(v.y, h1, q1);
            split_bf16(v.z, h2, q2); split_bf16(v.w, h3, q3);
            *(short4*)&Ah[ar][aq] = make_short4((short)h0,(short)h1,(short)h2,(short)h3);
            *(short4*)&Al[ar][aq] = make_short4((short)q0,(short)q1,(short)q2,(short)q3);
        }
#pragma unroll
        for (int it2 = 0; it2 < 2; ++it2) {
            int item = it2 * 256 + tid;
            int q  = item >> 4;
            int kp = item & 15;
            const unsigned short* sh = Bh + (size_t)(k0 + 2 * kp) * ldb + col0 + q * 4;
            const unsigned short* sl = Bl + (size_t)(k0 + 2 * kp) * ldb + col0 + q * 4;
            ushort4 h0 = *(const ushort4*)sh;
            ushort4 h1 = *(const ushort4*)(sh + ldb);
            ushort4 l0 = *(const ushort4*)sl;
            ushort4 l1 = *(const ushort4*)(sl + ldb);
            unsigned short h0a[4] = {h0.x, h0.y, h0.z, h0.w};
            unsigned short h1a[4] = {h1.x, h1.y, h1.z, h1.w};
            unsigned short l0a[4] = {l0.x, l0.y, l0.z, l0.w};
            unsigned short l1a[4] = {l1.x, l1.y, l1.z, l1.w};
#pragma unroll
            for (int cc = 0; cc < 4; ++cc) {
                int col = q * 4 + cc;
                *(unsigned*)&Bhs[col][2 * kp] = (unsigned)h0a[cc] | ((unsigned)h1a[cc] << 16);
                *(unsigned*)&Bls[col][2 * kp] = (unsigned)l0a[cc] | ((unsigned)l1a[cc] << 16);
            }
        }
        __syncthreads();

        bf16x8 ah[4], al4[4], bh[4], bl4[4];
#pragma unroll
        for (int mt = 0; mt < 4; ++mt) {
            ah[mt]  = *(const bf16x8*)&Ah[wm + mt * 16 + fr][fk];
            al4[mt] = *(const bf16x8*)&Al[wm + mt * 16 + fr][fk];
        }
#pragma unroll
        for (int nt = 0; nt < 4; ++nt) {
            bh[nt]  = *(const bf16x8*)&Bhs[wn + nt * 16 + fr][fk];
            bl4[nt] = *(const bf16x8*)&Bls[wn + nt * 16 + fr][fk];
        }
#pragma unroll
        for (int mt = 0; mt < 4; ++mt)
#pragma unroll
            for (int nt = 0; nt < 4; ++nt) {
                acc[mt][nt] = __builtin_amdgcn_mfma_f32_16x16x32_bf16(ah[mt],  bh[nt],  acc[mt][nt], 0, 0, 0);
                acc[mt][nt] = __builtin_amdgcn_mfma_f32_16x16x32_bf16(al4[mt], bh[nt],  acc[mt][nt], 0, 0, 0);
                acc[mt][nt] = __builtin_amdgcn_mfma_f32_16x16x32_bf16(ah[mt],  bl4[nt], acc[mt][nt], 0, 0, 0);
            }
        __syncthreads();
    }
#pragma unroll
    for (int mt = 0; mt < 4; ++mt) {
        int row = row0 + wm + mt * 16 + (l >> 4) * 4;
#pragma unroll
        for (int nt = 0; nt < 4; ++nt) {
            int col = col0 + wn + nt * 16 + fr;
#pragma unroll
            for (int j = 0; j < 4; ++j) {
                size_t idx = (size_t)(row + j) * ldc + col;
                if (ACC) C[idx] += acc[mt][nt][j];
                else     C[idx]  = acc[mt][nt][j];
            }
        }
    }
}

// ---------------- f32 GEMM: C (+)= exp(A) @ B (tiny N=64 Y-GEMM), LOG fuses final log ----------------
template<int ACC, int LOG>
__global__ __launch_bounds__(256)
void gemm_ab(const float* __restrict__ A, int lda,
             const float* __restrict__ B, int ldb,
             float* __restrict__ C, int ldc, int K,
             const float* __restrict__ cm, const float* __restrict__ ciz)
{
    __shared__ float As[16][128];
    __shared__ float Bs[16][64];
    const int row0 = blockIdx.y * 128;
    const int col0 = blockIdx.x * 64;
    const int tid = threadIdx.x;
    const int tr = tid >> 4, tc = tid & 15;
    float acc[8][4];
#pragma unroll
    for (int i = 0; i < 8; ++i)
#pragma unroll
        for (int j = 0; j < 4; ++j) acc[i][j] = 0.0f;

    for (int k0 = 0; k0 < K; k0 += 16) {
#pragma unroll
        for (int p = tid; p < 512; p += 256) {
            int r = p >> 2, kq = (p & 3) * 4;
            float4 av = *(const float4*)(A + (size_t)(row0 + r) * lda + k0 + kq);
            int kk = k0 + kq;
            av.x = expf(av.x - cm[kk + 0]) * ciz[kk + 0];
            av.y = expf(av.y - cm[kk + 1]) * ciz[kk + 1];
            av.z = expf(av.z - cm[kk + 2]) * ciz[kk + 2];
            av.w = expf(av.w - cm[kk + 3]) * ciz[kk + 3];
            As[kq + 0][r] = av.x; As[kq + 1][r] = av.y; As[kq + 2][r] = av.z; As[kq + 3][r] = av.w;
        }
        {
            int kr = tid >> 4, cq = (tid & 15) * 4;
            float4 bv = *(const float4*)(B + (size_t)(k0 + kr) * ldb + col0 + cq);
            *(float4*)&Bs[kr][cq] = bv;
        }
        __syncthreads();
#pragma unroll
        for (int kk = 0; kk < 16; ++kk) {
            float4 a0 = *(const float4*)&As[kk][tr * 8];
            float4 a1 = *(const float4*)&As[kk][tr * 8 + 4];
            float4 b0 = *(const float4*)&Bs[kk][tc * 4];
            float a[8] = {a0.x, a0.y, a0.z, a0.w, a1.x, a1.y, a1.z, a1.w};
            float b[4] = {b0.x, b0.y, b0.z, b0.w};
#pragma unroll
            for (int i = 0; i < 8; ++i)
#pragma unroll
                for (int j = 0; j < 4; ++j) acc[i][j] += a[i] * b[j];
        }
        __syncthreads();
    }
#pragma unroll
    for (int i = 0; i < 8; ++i) {
        size_t idx = (size_t)(row0 + tr * 8 + i) * ldc + col0 + tc * 4;
#pragma unroll
        for (int j = 0; j < 4; ++j) {
            float v = ACC ? (C[idx + j] + acc[i][j]) : acc[i][j];
            C[idx + j] = LOG ? logf(v) : v;
        }
    }
}

// ---------------- persistent bidirectional LSTM (r10/r12 proven version) ----------------
__global__ __launch_bounds__(256, 1)
void lstm_persist(const float* __restrict__ Xf, const float* __restrict__ Xb,
                  const float* __restrict__ Wf, const float* __restrict__ Wb,
                  float* __restrict__ Hf, float* __restrict__ Hb)
{
    __shared__ float w_lds[64 * FEAT];   // 128 KB: row (e*4+g), col k
    __shared__ float hs[2][FEAT];

    const int bid = blockIdx.x;
    const int dir = bid >> 5;
    const int blk = bid & 31;
    const int tid = threadIdx.x;
    const float* W = dir ? Wb : Wf;
    const float* X = dir ? Xb : Xf;
    float* H = dir ? Hb : Hf;

    for (int idx = tid * 4; idx < 64 * FEAT; idx += 1024) {
        int row_ld = idx >> 9, col = idx & 511;
        int grow = (row_ld & 3) * FEAT + blk * 16 + (row_ld >> 2);
        float4 wv = *(const float4*)(W + (size_t)grow * FEAT + col);
        *(float4*)&w_lds[row_ld * FEAT + col] = wv;
    }
    __syncthreads();

    const int e = tid >> 4, l = tid & 15;
    const int hidx = blk * 16 + e;
    float c_reg = 0.0f;

    for (int t = 0; t < NS; ++t) {
        const int trow = dir ? (NS - 1 - t) : t;
        const float* Xrow = X + (size_t)trow * G4;
        float x0 = 0.f, x1 = 0.f, x2 = 0.f, x3 = 0.f;
        if (l == 0) {
            x0 = Xrow[hidx];            x1 = Xrow[FEAT + hidx];
            x2 = Xrow[2 * FEAT + hidx]; x3 = Xrow[3 * FEAT + hidx];
        }
        float* hcur = hs[t & 1];
        if (t > 0) {
            const int prow = dir ? (trow + 1) : (trow - 1);
            const float* Hp = H + (size_t)prow * FEAT;
            float v0, v1;
            do {
                v0 = __hip_atomic_load(Hp + tid,       __ATOMIC_RELAXED, __HIP_MEMORY_SCOPE_AGENT);
                v1 = __hip_atomic_load(Hp + tid + 256, __ATOMIC_RELAXED, __HIP_MEMORY_SCOPE_AGENT);
            } while (v0 == SENT || v1 == SENT);
            hcur[tid] = v0; hcur[tid + 256] = v1;
        } else {
            hcur[tid] = 0.0f; hcur[tid + 256] = 0.0f;
        }
        __syncthreads();

        float dots[4];
#pragma unroll
        for (int g = 0; g < 4; ++g) {
            const float* w = &w_lds[(e * 4 + g) * FEAT];
            float s = 0.0f;
#pragma unroll
            for (int j = 0; j < 8; ++j) {
                int col = l * 4 + j * 64;
                float4 wv = *(const float4*)&w[col];
                float4 hv = *(const float4*)&hcur[col];
                s += wv.x * hv.x + wv.y * hv.y + wv.z * hv.z + wv.w * hv.w;
            }
#pragma unroll
            for (int off = 8; off >= 1; off >>= 1) s += __shfl_xor(s, off, 64);
            dots[g] = s;
        }
        if (l == 0) {
            float gi = dots[0] + x0, gf = dots[1] + x1;
            float gg = dots[2] + x2, go = dots[3] + x3;
            float cn = sigf(gf) * c_reg + sigf(gi) * tanhf(gg);
            float hv = sigf(go) * tanhf(cn);
            c_reg = cn;
            __hip_atomic_store(H + (size_t)trow * FEAT + hidx, hv,
                               __ATOMIC_RELAXED, __HIP_MEMORY_SCOPE_AGENT);
        }
    }
}

// ---------------- fused G assembly + row-normalize -> bf16 pairs ----------------
__global__ __launch_bounds__(256)
void gnorm_fuse(const float* __restrict__ S, const float* __restrict__ Hf,
                const float* __restrict__ Hb,
                unsigned short* __restrict__ Gh, unsigned short* __restrict__ Gl,
                unsigned short* __restrict__ Gnh, unsigned short* __restrict__ Gnl)
{
    const int row = blockIdx.x;
    const size_t base = (size_t)row * FEAT;
    const int tid = threadIdx.x;
    float v0 = S[base + tid]       + Hf[base + tid]       + Hb[base + tid];
    float v1 = S[base + tid + 256] + Hf[base + tid + 256] + Hb[base + tid + 256];
    float s = v0 * v0 + v1 * v1;
#pragma unroll
    for (int off = 32; off >= 1; off >>= 1) s += __shfl_xor(s, off, 64);
    __shared__ float red[4];
    if ((tid & 63) == 0) red[tid >> 6] = s;
    __syncthreads();
    float tot = red[0] + red[1] + red[2] + red[3];
    float inv = 1.0f / (sqrtf(tot) + 1e-5f);
    unsigned short h, l;
    split_bf16(v0, h, l);        Gh[base + tid] = h;        Gl[base + tid] = l;
    split_bf16(v1, h, l);        Gh[base + tid + 256] = h;  Gl[base + tid + 256] = l;
    split_bf16(v0 * inv, h, l);  Gnh[base + tid] = h;       Gnl[base + tid] = l;
    split_bf16(v1 * inv, h, l);  Gnh[base + tid + 256] = h; Gnl[base + tid + 256] = l;
}

// ---------------- column softmax stats over a [NQ x slab] buffer ----------------
__global__ __launch_bounds__(256)
void colstats_partial(const float* __restrict__ A, float* __restrict__ pm,
                      float* __restrict__ pz, int slab)
{
    const int col = blockIdx.x * 256 + threadIdx.x;
    const int r0 = blockIdx.y * 128;
    float m = -3.0e38f, z = 0.0f;
    for (int r = 0; r < 128; ++r) {
        float v = A[(size_t)(r0 + r) * slab + col];
        if (v > m) { z = z * expf(m - v) + 1.0f; m = v; }
        else       { z += expf(v - m); }
    }
    pm[(size_t)blockIdx.y * slab + col] = m;
    pz[(size_t)blockIdx.y * slab + col] = z;
}

__global__ __launch_bounds__(256)
void colstats_combine(const float* __restrict__ pm, const float* __restrict__ pz,
                      float* __restrict__ cm, float* __restrict__ ciz, int slab)
{
    const int col = blockIdx.x * 256 + threadIdx.x;
    float m = -3.0e38f;
    for (int p = 0; p < 64; ++p) m = fmaxf(m, pm[(size_t)p * slab + col]);
    float z = 0.0f;
    for (int p = 0; p < 64; ++p) z += pz[(size_t)p * slab + col] * expf(pm[(size_t)p * slab + col] - m);
    cm[col] = m;
    ciz[col] = 1.0f / z;
}

// ---------------- FCE cell on one k-slice; writes h as bf16 hi/lo pair ----------------
__global__ void cell_slice(const float* __restrict__ gslab, float* __restrict__ cst,
                           unsigned short* __restrict__ hh, unsigned short* __restrict__ hl,
                           const float* __restrict__ f,
                           int k0, int ldg, int kshift)
{
    int i = blockIdx.x * blockDim.x + threadIdx.x;
    const int st = gridDim.x * blockDim.x;
    const int n = NQ << kshift;
    const int kmask = (1 << kshift) - 1;
    for (; i < n; i += st) {
        int q = i >> kshift, kk = i & kmask;
        float4 g = *(const float4*)(gslab + (size_t)q * ldg + kk * 4);
        int idx = q * FEAT + k0 + kk;
        float cold = cst[idx];
        float cn = sigf(g.y) * cold + sigf(g.x) * tanhf(g.z);
        float hn = sigf(g.w) * tanhf(cn) + f[idx];
        cst[idx] = cn;
        unsigned short ph, pl;
        split_bf16(hn, ph, pl);
        hh[idx] = ph; hl[idx] = pl;
    }
}

// ---------------- launch ----------------
extern "C" void kernel_launch(void* const* d_in, const int* in_sizes, int n_in,
                              void* d_out, int out_size, void* d_ws, size_t ws_size,
                              hipStream_t stream)
{
    (void)in_sizes; (void)n_in; (void)out_size;
    const float* S     = (const float*)d_in[0];
    const float* f     = (const float*)d_in[1];
    const float* Y     = (const float*)d_in[2];
    const float* Wf_ih = (const float*)d_in[3];
    const float* Wf_hh = (const float*)d_in[4];
    const float* bf    = (const float*)d_in[5];
    const float* Wb_ih = (const float*)d_in[6];
    const float* Wb_hh = (const float*)d_in[7];
    const float* bb    = (const float*)d_in[8];
    const float* Wc_ih = (const float*)d_in[9];
    const float* Wc_hh = (const float*)d_in[10];
    const float* bc    = (const float*)d_in[11];
    float* out = (float*)d_out;

    // footprint tiers: slab1024+fpair=141MB, slab1024=125MB, slab512=109MB
    const bool big    = ws_size >= (size_t)142 * 1024 * 1024;
    const bool mid    = ws_size >= (size_t)126 * 1024 * 1024;
    const int  slab   = (big || mid) ? 1024 : 512;
    const bool fpair  = big;
    const int nslab  = NS / slab;
    const int nslice = 2048 / slab;
    const int kwidth = slab / 4;
    const int kshift = (slab == 1024) ? 8 : 7;

    float* ws = (float*)d_ws;
    // region 0: 16M floats — phase A/B: Xf|Xb ; phase C: r|cst|h-pair0|h-pair1
    float* Xf   = ws;
    float* Xb   = ws + (size_t)8 * 1024 * 1024;
    float* r    = ws;
    float* cst  = ws + (size_t)4 * 1024 * 1024;
    unsigned short* p0h = (unsigned short*)(ws + (size_t)8 * 1024 * 1024);
    unsigned short* p0l = (unsigned short*)(ws + (size_t)10 * 1024 * 1024);
    unsigned short* p1h = (unsigned short*)(ws + (size_t)12 * 1024 * 1024);
    unsigned short* p1l = (unsigned short*)(ws + (size_t)14 * 1024 * 1024);
    size_t off  = (size_t)16 * 1024 * 1024;
    auto alloc = [&](size_t n) { float* p = ws + off; off += n; return p; };
    float* Pslab = alloc((size_t)NQ * slab);
    unsigned short* Gh  = (unsigned short*)alloc(1024 * 1024);
    unsigned short* Gl  = (unsigned short*)alloc(1024 * 1024);
    unsigned short* Gnh = (unsigned short*)alloc(1024 * 1024);
    unsigned short* Gnl = (unsigned short*)alloc(1024 * 1024);
    unsigned short* Wph = (unsigned short*)alloc(1536 * 1024);
    unsigned short* Wpl = (unsigned short*)alloc(1536 * 1024);
    float* bpack = alloc(G4);
    float* pm    = alloc((size_t)64 * 1024);
    float* pz    = alloc((size_t)64 * 1024);
    float* cm    = alloc(1024);
    float* ciz   = alloc(1024);
    unsigned short* fh = nullptr; unsigned short* fl = nullptr;
    if (fpair) {
        fh = (unsigned short*)alloc(2 * 1024 * 1024);   // NQ*FEAT shorts
        fl = (unsigned short*)alloc(2 * 1024 * 1024);
    }

    float* Hf = Pslab;
    float* Hb = Pslab + (size_t)2 * 1024 * 1024;

    const dim3 B256(256);

    // ---- Phase A: Xf = S@Wf_ih^T+bf, Xb = S@Wb_ih^T+bb ----
    mm_abt_f32<1><<<dim3(16, 32), B256, 0, stream>>>(S, Wf_ih, FEAT, FEAT, Xf, G4, bf, FEAT);
    mm_abt_f32<1><<<dim3(16, 32), B256, 0, stream>>>(S, Wb_ih, FEAT, FEAT, Xb, G4, bb, FEAT);

    // ---- Phase B: persistent bidirectional LSTM ----
    kfill<<<dim3(2048), B256, 0, stream>>>(Pslab, SENT, 4 * 1024 * 1024);  // Hf+Hb sentinel
    lstm_persist<<<dim3(64), B256, 0, stream>>>(Xf, Xb, Wf_hh, Wb_hh, Hf, Hb);
    gnorm_fuse<<<dim3(NS), B256, 0, stream>>>(S, Hf, Hb, Gh, Gl, Gnh, Gnl);

    // ---- Phase C prep ----
    pack_w<<<dim3(2048), B256, 0, stream>>>(Wph, Wpl, bpack, Wc_ih, Wc_hh, bc);
    kzero<<<dim3(1024), B256, 0, stream>>>(cst, NQ * FEAT);     // c = 0
    if (fpair)
        split_arr<<<dim3(2048), B256, 0, stream>>>(f, fh, fl, NQ * FEAT);

    // ---- Phase C: K=3 FCE iterations (h0 = f) ----
    for (int it = 0; it < 3; ++it) {
        const unsigned short* hch = (it == 1) ? p0h : p1h;   // iter2 reads p1
        const unsigned short* hcl = (it == 1) ? p0l : p1l;
        unsigned short* hxh = (it == 1) ? p1h : p0h;         // iter0->p0, iter1->p1, iter2->p0
        unsigned short* hxl = (it == 1) ? p1l : p0l;
        for (int sb = 0; sb < nslab; ++sb) {
            const unsigned short* Gsh = Gh + (size_t)sb * slab * FEAT;
            const unsigned short* Gsl = Gl + (size_t)sb * slab * FEAT;
            if (it == 0) {
                if (fpair)
                    mm_abt3<0,0><<<dim3(slab / 128, 64), B256, 0, stream>>>(fh, fl, nullptr, nullptr, nullptr, nullptr,
                                                                            Gsh, Gsl, FEAT, FEAT, Pslab, slab, nullptr, FEAT);
                else
                    mm_abt2<0,0><<<dim3(slab / 128, 64), B256, 0, stream>>>(f, nullptr, nullptr, Gsh, Gsl,
                                                                            FEAT, FEAT, Pslab, slab, nullptr, FEAT);
            } else {
                mm_abt3<0,0><<<dim3(slab / 128, 64), B256, 0, stream>>>(hch, hcl, nullptr, nullptr, nullptr, nullptr,
                                                                        Gsh, Gsl, FEAT, FEAT, Pslab, slab, nullptr, FEAT);
            }
            colstats_partial<<<dim3(slab / 256, 64), B256, 0, stream>>>(Pslab, pm, pz, slab);
            colstats_combine<<<dim3(slab / 256), B256, 0, stream>>>(pm, pz, cm, ciz, slab);
            if (sb == 0) mm_ab2<0><<<dim3(4, 64), B256, 0, stream>>>(Pslab, slab, Gsh, Gsl, FEAT, r, FEAT, slab, cm, ciz);
            else         mm_ab2<1><<<dim3(4, 64), B256, 0, stream>>>(Pslab, slab, Gsh, Gsl, FEAT, r, FEAT, slab, cm, ciz);
        }
        for (int sl = 0; sl < nslice; ++sl) {
            const unsigned short* Wsh = Wph + (size_t)sl * slab * 1536;
            const unsigned short* Wsl = Wpl + (size_t)sl * slab * 1536;
            if (fpair) {
                const unsigned short* hhp = (it == 0) ? fh : hch;
                const unsigned short* hlp = (it == 0) ? fl : hcl;
                mm_abt3<1,2><<<dim3(slab / 128, 64), B256, 0, stream>>>(hhp, hlp, fh, fl, nullptr, r,
                                                                        Wsh, Wsl, FEAT, 1536, Pslab, slab, bpack + sl * slab, 1536);
            } else {
                if (it == 0)
                    mm_abt2<1,1><<<dim3(slab / 128, 64), B256, 0, stream>>>(f, r, f, Wsh, Wsl,
                                                                            FEAT, 1536, Pslab, slab, bpack + sl * slab, 1536);
                else
                    mm_abt3<1,1><<<dim3(slab / 128, 64), B256, 0, stream>>>(hch, hcl, nullptr, nullptr, f, r,
                                                                            Wsh, Wsl, FEAT, 1536, Pslab, slab, bpack + sl * slab, 1536);
            }
            cell_slice<<<dim3(2048), B256, 0, stream>>>(Pslab, cst, hxh, hxl, f, sl * kwidth, slab, kshift);
        }
    }

    // ---- Phase D: out = log(softmax_col(h @ Gn^T) @ Y); h = pair0 (after iter 2) ----
    for (int sb = 0; sb < nslab; ++sb) {
        const unsigned short* Gsh = Gnh + (size_t)sb * slab * FEAT;
        const unsigned short* Gsl = Gnl + (size_t)sb * slab * FEAT;
        mm_abt3<0,0><<<dim3(slab / 128, 64), B256, 0, stream>>>(p0h, p0l, nullptr, nullptr, nullptr, nullptr,
                                                                Gsh, Gsl, FEAT, FEAT, Pslab, slab, nullptr, FEAT);
        colstats_partial<<<dim3(slab / 256, 64), B256, 0, stream>>>(Pslab, pm, pz, slab);
        colstats_combine<<<dim3(slab / 256), B256, 0, stream>>>(pm, pz, cm, ciz, slab);
        const float* Ys = Y + (size_t)sb * slab * NC;
        if (nslab == 1)           gemm_ab<0,1><<<dim3(1, 64), B256, 0, stream>>>(Pslab, slab, Ys, NC, out, NC, slab, cm, ciz);
        else if (sb == 0)         gemm_ab<0,0><<<dim3(1, 64), B256, 0, stream>>>(Pslab, slab, Ys, NC, out, NC, slab, cm, ciz);
        else if (sb == nslab - 1) gemm_ab<1,1><<<dim3(1, 64), B256, 0, stream>>>(Pslab, slab, Ys, NC, out, NC, slab, cm, ciz);
        else                      gemm_ab<1,0><<<dim3(1, 64), B256, 0, stream>>>(Pslab, slab, Ys, NC, out, NC, slab, cm, ciz);
    }
}